// Round 8
// baseline (340.154 us; speedup 1.0000x reference)
//
#include <hip/hip_runtime.h>
#include <math.h>

// Problem constants
#define NB   8      // batch
#define HH   256
#define WW   256
#define CY   8      // y channels
#define HO   128
#define WO   128
#define OCN  512    // dcn output channels
#define K2   9
#define KJ   72     // 8*9 reduction length
#define KP   104    // padded cols row length (bf16): 72 real + zeros; 208B rows

typedef short bf16x8 __attribute__((ext_vector_type(8)));
typedef float f32x4  __attribute__((ext_vector_type(4)));

static __device__ inline unsigned short f2bf(float f) {
    union { float f; unsigned u; } v; v.f = f;
    unsigned r = (v.u + 0x7FFFu + ((v.u >> 16) & 1u)) >> 16;   // RNE
    return (unsigned short)r;
}

// ---------------- Kernel A: y = leaky(conv1x1(x) + b), stored NHWC(8) ----------------
__global__ __launch_bounds__(256) void k_conv1(const float* __restrict__ x,
                                               const float* __restrict__ w,
                                               const float* __restrict__ b,
                                               float* __restrict__ y) {
    int idx = blockIdx.x * 256 + threadIdx.x;      // n*65536 + h*256 + w
    int n = idx >> 16, hw = idx & 65535;
    const float* xp = x + (size_t)n * 3 * 65536 + hw;
    float x0 = xp[0], x1 = xp[65536], x2 = xp[131072];
    float o[8];
#pragma unroll
    for (int oc = 0; oc < 8; ++oc) {
        float v = fmaf(w[oc*3+0], x0, fmaf(w[oc*3+1], x1, fmaf(w[oc*3+2], x2, b[oc])));
        o[oc] = v >= 0.f ? v : 0.1f * v;
    }
    float* yp = y + (size_t)idx * 8;
    *(float4*)(yp + 0) = make_float4(o[0], o[1], o[2], o[3]);
    *(float4*)(yp + 4) = make_float4(o[4], o[5], o[6], o[7]);
}

// ---------------- Kernel D: pad/convert dcn_w fp32[512][72] -> bf16[512][104] ----------------
__global__ __launch_bounds__(256) void k_wpad(const float* __restrict__ wd,
                                              unsigned short* __restrict__ wdb) {
    int i = blockIdx.x * 256 + threadIdx.x;        // exactly 208*256 = 53248 = 512*104
    int row = i / KP;
    int k = i - row * KP;
    float v = (k < KJ) ? wd[row * KJ + k] : 0.f;
    wdb[i] = f2bf(v);
}

// ---------------- Fused kernel: offset conv + sampling (verbatim round-6 math) + MFMA ----------------
// Block = 512 threads (8 waves), 128 pixels (one output row of one image), all 512 oc.
// Phase 1 (t<128 only): EXACT round-6 per-pixel conv + bilinear sampling, cols -> LDS (bit-identical
//   to the verified 0.0078-absmax pipeline; round-7's parallel restructure changed rounding and failed).
// Phase 2 (8 waves): MFMA 16x16x32 bf16, 2 passes x 32 oc/wave, nontemporal stores.
__global__ __launch_bounds__(512, 4) void k_fused(const float* __restrict__ y,
                                                  const float* __restrict__ ow,
                                                  const float* __restrict__ ob,
                                                  const unsigned short* __restrict__ wdb,
                                                  float* __restrict__ out) {
    __shared__ __align__(16) unsigned short cT[128 * KP];   // 26624 B

    int t = threadIdx.x;
    int pix0 = blockIdx.x * 128;         // tile = one full output row
    int nimg = pix0 >> 14;
    int ho   = (pix0 & 16383) >> 7;
    const float* yn = y + (size_t)nimg * (HH * WW * CY);

    if (t < 128) {
        int wo = t;
        // ---- offset conv: verbatim round-6 expression tree ----
        float acc[27];
#pragma unroll
        for (int oc = 0; oc < 27; ++oc) acc[oc] = ob[oc];   // uniform -> s_load

#pragma unroll 1
        for (int pos = 0; pos < 9; ++pos) {
            int kh = pos / 3, kw = pos - kh * 3;
            int hi = 2 * ho - 1 + kh, wi = 2 * wo - 1 + kw;
            float4 a  = make_float4(0.f, 0.f, 0.f, 0.f);
            float4 c4 = make_float4(0.f, 0.f, 0.f, 0.f);
            if ((unsigned)hi < 256u && (unsigned)wi < 256u) {
                const float* yp = yn + ((size_t)hi * 256 + wi) * 8;
                a  = *(const float4*)(yp + 0);
                c4 = *(const float4*)(yp + 4);
            }
            const float* wp = ow + pos;                // + oc*72 + c*9 (uniform)
#pragma unroll
            for (int oc = 0; oc < 27; ++oc) {
                float s = fmaf(wp[oc*72 + 0*9], a.x,
                          fmaf(wp[oc*72 + 1*9], a.y,
                          fmaf(wp[oc*72 + 2*9], a.z,
                          fmaf(wp[oc*72 + 3*9], a.w,
                          fmaf(wp[oc*72 + 4*9], c4.x,
                          fmaf(wp[oc*72 + 5*9], c4.y,
                          fmaf(wp[oc*72 + 6*9], c4.z,
                               wp[oc*72 + 7*9] * c4.w)))))));
                acc[oc] += s;
            }
        }

        // ---- bilinear sampling + mask: verbatim round-6, writes LDS row ----
#pragma unroll
        for (int k = 0; k < 9; ++k) {
            float dy = acc[2 * k], dx = acc[2 * k + 1];
            float m  = 1.f / (1.f + expf(-acc[18 + k]));
            float py = (float)(2 * ho - 1 + (k / 3)) + dy;
            float px = (float)(2 * wo - 1 + (k % 3)) + dx;
            float y0f = floorf(py), x0f = floorf(px);
            float fy = py - y0f, fx = px - x0f;
            int y0 = (int)y0f, x0 = (int)x0f;
            float s0=0,s1=0,s2=0,s3=0,s4=0,s5=0,s6=0,s7=0;
#pragma unroll
            for (int oy = 0; oy < 2; ++oy) {
#pragma unroll
                for (int ox = 0; ox < 2; ++ox) {
                    int yy = y0 + oy, xx = x0 + ox;
                    float wgt = (oy ? fy : 1.f - fy) * (ox ? fx : 1.f - fx);
                    if ((unsigned)yy < 256u && (unsigned)xx < 256u) {
                        const float* yp = yn + ((size_t)yy * 256 + xx) * 8;
                        float4 a  = *(const float4*)(yp + 0);
                        float4 c4 = *(const float4*)(yp + 4);
                        s0 = fmaf(wgt, a.x,  s0); s1 = fmaf(wgt, a.y,  s1);
                        s2 = fmaf(wgt, a.z,  s2); s3 = fmaf(wgt, a.w,  s3);
                        s4 = fmaf(wgt, c4.x, s4); s5 = fmaf(wgt, c4.y, s5);
                        s6 = fmaf(wgt, c4.z, s6); s7 = fmaf(wgt, c4.w, s7);
                    }
                }
            }
            unsigned short* cp = cT + t * KP + k;
            cp[0*9] = f2bf(m*s0); cp[1*9] = f2bf(m*s1); cp[2*9] = f2bf(m*s2); cp[3*9] = f2bf(m*s3);
            cp[4*9] = f2bf(m*s4); cp[5*9] = f2bf(m*s5); cp[6*9] = f2bf(m*s6); cp[7*9] = f2bf(m*s7);
        }
        // zero pad k = 72..103 (bytes 144..207 of this row)
        {
            uint4 z; z.x = z.y = z.z = z.w = 0u;
            uint4* zp = (uint4*)((unsigned char*)cT + (size_t)t * 2 * KP + 144);
            zp[0] = z; zp[1] = z; zp[2] = z; zp[3] = z;
        }
    }
    __syncthreads();

    // ---------------- phase 2: MFMA GEMM (value-identical to verified round-6 GEMM) ----------------
    int wave = t >> 6, lane = t & 63, lr = lane & 15, lk = lane >> 4;
    int hwbase = pix0 & 16383;
#pragma unroll
    for (int p = 0; p < 2; ++p) {
        int ocb = p * 256 + wave * 32;
        bf16x8 aF[2][3];
#pragma unroll
        for (int m = 0; m < 2; ++m)
#pragma unroll
            for (int kk = 0; kk < 3; ++kk)
                aF[m][kk] = *(const bf16x8*)(wdb + (size_t)(ocb + m * 16 + lr) * KP + kk * 32 + lk * 8);

        f32x4 acc2[2][8];
#pragma unroll
        for (int m = 0; m < 2; ++m)
#pragma unroll
            for (int n = 0; n < 8; ++n) acc2[m][n] = (f32x4){0.f, 0.f, 0.f, 0.f};

#pragma unroll
        for (int kk = 0; kk < 3; ++kk) {
#pragma unroll
            for (int n = 0; n < 8; ++n) {
                bf16x8 bF = *(const bf16x8*)(cT + (n * 16 + lr) * KP + kk * 32 + lk * 8);
                acc2[0][n] = __builtin_amdgcn_mfma_f32_16x16x32_bf16(aF[0][kk], bF, acc2[0][n], 0, 0, 0);
                acc2[1][n] = __builtin_amdgcn_mfma_f32_16x16x32_bf16(aF[1][kk], bF, acc2[1][n], 0, 0, 0);
            }
        }

        // D: col = lane&15 = pixel, row = lk*4+reg = oc (m89 layout). Nontemporal stores.
#pragma unroll
        for (int m = 0; m < 2; ++m) {
            int oc = ocb + m * 16 + lk * 4;
#pragma unroll
            for (int n = 0; n < 8; ++n) {
                int hw = hwbase + n * 16 + lr;
                float* op = out + ((size_t)nimg * OCN + oc) * 16384 + hw;
                __builtin_nontemporal_store(acc2[m][n][0], op);
                __builtin_nontemporal_store(acc2[m][n][1], op + 16384);
                __builtin_nontemporal_store(acc2[m][n][2], op + 2 * 16384);
                __builtin_nontemporal_store(acc2[m][n][3], op + 3 * 16384);
            }
        }
    }
}

extern "C" void kernel_launch(void* const* d_in, const int* in_sizes, int n_in,
                              void* d_out, int out_size, void* d_ws, size_t ws_size,
                              hipStream_t stream) {
    const float* x   = (const float*)d_in[0];
    const float* c1w = (const float*)d_in[1];
    const float* c1b = (const float*)d_in[2];
    const float* ow  = (const float*)d_in[3];
    const float* ob  = (const float*)d_in[4];
    const float* dw  = (const float*)d_in[5];
    float* out = (float*)d_out;

    // ws layout: y fp32 16,777,216 B ; wdb bf16 106,496 B
    float* yb = (float*)d_ws;
    unsigned short* wdb = (unsigned short*)((unsigned char*)d_ws + 16777216);

    hipLaunchKernelGGL(k_conv1, dim3(2048), dim3(256), 0, stream, x, c1w, c1b, yb);
    hipLaunchKernelGGL(k_wpad, dim3(208), dim3(256), 0, stream, dw, wdb);
    hipLaunchKernelGGL(k_fused, dim3(1024), dim3(512), 0, stream, yb, ow, ob, wdb, out);
}